// Round 14
// baseline (32.748 us; speedup 1.0000x reference)
//
#include <hip/hip_runtime.h>

#define B 32
#define L 512
#define D 768
#define M 24
#define P (M * (M - 1))     // 552
#define ROWS 16             // K2 rows per block
#define NROW (B * P)        // 17664 total rows (divisible by 16)

typedef float f32x2 __attribute__((ext_vector_type(2)));
typedef float f32x4 __attribute__((ext_vector_type(4)));

// K1 (read phase): one block per mention, 384 threads, one f32x2 column each.
// Full-span parallel gather (15 clamped unconditional loads, masked adds).
// Writes pooled (2.4 MB, stays L2/L3-hot) and the 5-float pair rows.
__global__ void __launch_bounds__(384)
pool_kernel(const float* __restrict__ seq,   // B,L,D
            const int*   __restrict__ head,  // B,L
            const int*   __restrict__ em,    // B,M,2
            float*       __restrict__ pooled,// B,M,D
            float*       __restrict__ pout)  // B*P*5
{
    int g = blockIdx.x;            // 0..767 mention id
    int b = g / M, m = g - b * M;
    int t = threadIdx.x;           // 0..383 f32x2 column

    const int* emb = em + b * M * 2;
    int s = emb[2 * m];
    int e = emb[2 * m + 1];
    int len = e - s;               // 1..15

    const float* seqb  = seq  + (size_t)b * L * D;
    const int*   headb = head + b * L;

    int hidx[15];
    #pragma unroll
    for (int r = 0; r < 15; ++r) {
        int l = s + r; l = (l < e) ? l : s;   // clamp -> unconditional
        hidx[r] = headb[l];
    }
    f32x2 vv[15];
    #pragma unroll
    for (int r = 0; r < 15; ++r)
        vv[r] = ((const f32x2*)(seqb + (size_t)hidx[r] * D))[t];
    f32x2 acc = (f32x2)(0.f);
    #pragma unroll
    for (int r = 0; r < 15; ++r)
        acc += (r < len) ? vv[r] : (f32x2)(0.f);
    acc *= 1.0f / (float)len;

    ((f32x2*)pooled)[(size_t)g * 384 + t] = acc;

    if (t < 23) {
        int rr = t;
        int j = (rr < m) ? rr : rr + 1;
        float* o = pout + ((size_t)b * P + (size_t)m * 23 + rr) * 5;
        o[0] = (float)b;
        o[1] = (float)s;
        o[2] = (float)e;
        o[3] = (float)emb[2 * j];
        o[4] = (float)emb[2 * j + 1];
    }
}

// K2 (write phase): 1104 blocks x 384 threads, 16 rows each. Per iteration:
// one f32x4 read from L2/L3-hot pooled + one f32x4 store; a block iteration
// writes one complete 6 KB output row contiguously. No LDS, ~20 VGPR ->
// fill-kernel-like occupancy on the store stream.
__global__ void __launch_bounds__(384)
rel_kernel(const float* __restrict__ pooled,  // B,M,D
           float*       __restrict__ out)     // B*P*1536
{
    int blk  = blockIdx.x;          // 0..1103
    int row0 = blk * ROWS;
    int t    = threadIdx.x;         // 0..383 quad column
    int hf   = t >= 192;            // obj/sub half (wave-uniform)
    int tq   = t - 192 * hf;        // 0..191

    const f32x4* pq   = (const f32x4*)pooled;
    f32x4*       outq = (f32x4*)out;

    #pragma unroll 4
    for (int r = 0; r < ROWS; ++r) {
        int row = row0 + r;
        int b   = row / P;                   // magic-mul
        int p   = row - b * P;
        int i   = p / 23;                    // magic-mul
        int rr  = p - i * 23;
        int j   = (rr < i) ? rr : rr + 1;
        int src = hf ? j : i;
        f32x4 v = pq[(size_t)(b * M + src) * 192 + tq];
        outq[(size_t)row * 384 + t] = v;
    }
}

extern "C" void kernel_launch(void* const* d_in, const int* in_sizes, int n_in,
                              void* d_out, int out_size, void* d_ws, size_t ws_size,
                              hipStream_t stream) {
    const float* seq  = (const float*)d_in[0];
    const int*   head = (const int*)d_in[1];
    const int*   em   = (const int*)d_in[2];
    float* out    = (float*)d_out;
    float* pooled = (float*)d_ws;                 // B*M*D f32 = 2.36 MB

    pool_kernel<<<B * M, 384, 0, stream>>>(seq, head, em, pooled,
                                           out + (size_t)B * P * 2 * D);
    rel_kernel<<<NROW / ROWS, 384, 0, stream>>>(pooled, out);
}

// Round 15
// 25.801 us; speedup vs baseline: 1.2693x; 1.2693x over previous
//
#include <hip/hip_runtime.h>

#define B 32
#define L 512
#define D 768
#define M 24
#define P (M * (M - 1))   // 552

typedef float f32x2 __attribute__((ext_vector_type(2)));

// R12 structure + uniform-address gather (scalar head loads, saddr row loads).
// 1536 blocks x 384 threads. Block = (mention g, column-half chalf).
// Threads: rp = t>=192 (even/odd gather rows + store role), c = t-192*rp.
// LDS combine (3 KB) + one barrier, then 23 regular coalesced stores.
__global__ void __launch_bounds__(384, 8)
fused_kernel(const float* __restrict__ seq,   // B,L,D
             const int*   __restrict__ head,  // B,L
             const int*   __restrict__ em,    // B,M,2
             float*       __restrict__ out)   // B*P*1536 rel | B*P*5 pairs
{
    __shared__ f32x2 pool[2][192];   // 3 KB

    int blk   = blockIdx.x;          // 0..1535
    int g     = blk >> 1;            // mention id 0..767
    int chalf = blk & 1;             // column half
    int b = g / M, m = g - b * M;
    int t  = threadIdx.x;            // 0..383
    int rp = (t >= 192);             // even/odd gather parity + store role
    int c  = t - rp * 192;           // 0..191
    int col = chalf * 192 + c;       // global f32x2 column 0..383

    const float* seqb  = seq  + (size_t)b * L * D;
    const int*   headb = head + b * L;
    const int*   emb   = em   + b * M * 2;

    // block-uniform span bounds -> force into SGPRs so head loads go scalar
    int s = __builtin_amdgcn_readfirstlane(emb[2 * m]);
    int e = __builtin_amdgcn_readfirstlane(emb[2 * m + 1]);
    int len = e - s;                 // 1..15
    int cnt = (len - rp + 1) >> 1;   // rows this parity accumulates (<=8)

    // head indexes: uniform addresses -> s_load, hidx lives in SGPRs
    int hidx[8];
    #pragma unroll
    for (int r = 0; r < 8; ++r) {
        int l = s + rp + 2 * r;
        l = (l < e) ? l : s;         // clamp -> unconditional
        hidx[r] = __builtin_amdgcn_readfirstlane(headb[l]);
    }

    // row loads: SGPR base + shared per-lane voffset (col), all in flight
    f32x2 vv[8];
    #pragma unroll
    for (int r = 0; r < 8; ++r)
        vv[r] = ((const f32x2*)(seqb + (size_t)hidx[r] * D))[col];
    f32x2 acc = (f32x2)(0.f);
    #pragma unroll
    for (int r = 0; r < 8; ++r)
        acc += (r < cnt) ? vv[r] : (f32x2)(0.f);

    pool[rp][c] = acc;
    __syncthreads();
    f32x2 v = (pool[0][c] + pool[1][c]) * (1.0f / (float)len);

    // fan-out writes (regular stores; each wave writes 512 B contiguous)
    f32x2* outg = (f32x2*)out;       // rel rows: 768 f32x2 each
    size_t rowbase = (size_t)b * P;

    if (rp == 0) {
        // OBJ half of rows m*23 + r, granule offset col
        size_t q = (rowbase + (size_t)m * 23) * 768 + col;
        #pragma unroll
        for (int r = 0; r < 23; ++r) {
            outg[q] = v;
            q += 768;
        }
        if (chalf == 0 && c < 23) {
            int rr = c;
            int j = (rr < m) ? rr : rr + 1;
            float* o = out + (size_t)B * P * 2 * D
                     + (rowbase + (size_t)m * 23 + rr) * 5;
            o[0] = (float)b;
            o[1] = (float)s;
            o[2] = (float)e;
            o[3] = (float)emb[2 * j];
            o[4] = (float)emb[2 * j + 1];
        }
    } else {
        // SUB half: this mention is j == m; for each i != m, r = (m<i) ? m : m-1
        #pragma unroll
        for (int i = 0; i < M; ++i) {
            if (i == m) continue;
            int r = (m < i) ? m : m - 1;
            size_t row = rowbase + (size_t)i * 23 + r;
            outg[row * 768 + 384 + col] = v;
        }
    }
}

extern "C" void kernel_launch(void* const* d_in, const int* in_sizes, int n_in,
                              void* d_out, int out_size, void* d_ws, size_t ws_size,
                              hipStream_t stream) {
    const float* seq  = (const float*)d_in[0];
    const int*   head = (const int*)d_in[1];
    const int*   em   = (const int*)d_in[2];
    float* out = (float*)d_out;

    fused_kernel<<<B * M * 2, 384, 0, stream>>>(seq, head, em, out);  // 1536 blocks
}